// Round 9
// baseline (3613.592 us; speedup 1.0000x reference)
//
#include <hip/hip_runtime.h>

#define B 128
#define S 16
#define E 512
#define R 1000
#define K3 1536
#define NW0 1920
#define SCALE 0.04419417382415922f

static __device__ __forceinline__ float sigm(float x) { return 1.f / (1.f + expf(-x)); }
static __device__ __forceinline__ float4 f40() { return make_float4(0.f, 0.f, 0.f, 0.f); }

static __device__ __forceinline__ float brsum(float v, float* sb) {
  int tid = threadIdx.x;
  sb[tid] = v; __syncthreads();
  for (int s = 128; s > 0; s >>= 1) {
    if (tid < s) sb[tid] += sb[tid + s];
    __syncthreads();
  }
  float r = sb[0]; __syncthreads();
  return r;
}
static __device__ __forceinline__ float brmax(float v, float* sb) {
  int tid = threadIdx.x;
  sb[tid] = v; __syncthreads();
  for (int s = 128; s > 0; s >>= 1) {
    if (tid < s) sb[tid] = fmaxf(sb[tid], sb[tid + s]);
    __syncthreads();
  }
  float r = sb[0]; __syncthreads();
  return r;
}

static __device__ __forceinline__ void fma16(const float (*__restrict__ As)[64],
                                             const float (*__restrict__ Ws)[64],
                                             float acc[4][4], int tx, int ty) {
#pragma unroll
  for (int k = 0; k < 16; ++k) {
    float4 a4 = *(const float4*)&As[k][ty * 4];
    float4 w4 = *(const float4*)&Ws[k][tx * 4];
    acc[0][0] = fmaf(a4.x, w4.x, acc[0][0]); acc[0][1] = fmaf(a4.x, w4.y, acc[0][1]);
    acc[0][2] = fmaf(a4.x, w4.z, acc[0][2]); acc[0][3] = fmaf(a4.x, w4.w, acc[0][3]);
    acc[1][0] = fmaf(a4.y, w4.x, acc[1][0]); acc[1][1] = fmaf(a4.y, w4.y, acc[1][1]);
    acc[1][2] = fmaf(a4.y, w4.z, acc[1][2]); acc[1][3] = fmaf(a4.y, w4.w, acc[1][3]);
    acc[2][0] = fmaf(a4.z, w4.x, acc[2][0]); acc[2][1] = fmaf(a4.z, w4.y, acc[2][1]);
    acc[2][2] = fmaf(a4.z, w4.z, acc[2][2]); acc[2][3] = fmaf(a4.z, w4.w, acc[2][3]);
    acc[3][0] = fmaf(a4.w, w4.x, acc[3][0]); acc[3][1] = fmaf(a4.w, w4.y, acc[3][1]);
    acc[3][2] = fmaf(a4.w, w4.z, acc[3][2]); acc[3][3] = fmaf(a4.w, w4.w, acc[3][3]);
  }
}

// ---------- init: pos/worklist + zero pads for EW rows and WQKTT cols ----------
__global__ __launch_bounds__(256) void k_initwl(int* __restrict__ pos,
                                                int* __restrict__ wlb,
                                                int* __restrict__ wlL,
                                                int* __restrict__ wlR,
                                                float* __restrict__ EW,
                                                float* __restrict__ WQKTT) {
  int gid = blockIdx.x * 256 + threadIdx.x;
  if (gid < B * 16) pos[gid] = gid & 15;
  if (gid < NW0) {
    wlb[gid] = gid / 15; wlL[gid] = gid % 15; wlR[gid] = gid % 15 + 1;
  }
  if (gid < 24 * K3) EW[(size_t)1000 * K3 + gid] = 0.f;   // pad rows k=1000..1023
  if (gid < 512 * 24) {                                   // pad cols j=1000..1023
    int r_ = gid / 24, c_ = gid % 24;
    WQKTT[(size_t)r_ * 1024 + 1000 + c_] = 0.f;
  }
}

// ---------- generic GEMM: C[m,n] = sum_k A[row(m)*strideB+k]*W[n*E+k] + bias[n]
__global__ __launch_bounds__(256) void k_gemm(const float* __restrict__ A, int strideB, int M,
                                              const int* __restrict__ aidx,
                                              const float* __restrict__ W, int N,
                                              const float* __restrict__ bias,
                                              float* __restrict__ C, int ldc) {
  __shared__ float As[16][64], Ws[16][64];
  int tid = threadIdx.x, mBase = blockIdx.y * 64, nBase = blockIdx.x * 64;
  int tx = tid & 15, ty = tid >> 4, li = tid & 63, lk = (tid >> 6) * 4;
  float acc[4][4] = {};
  int m = mBase + li;
  const float* Arow = nullptr;
  if (m < M) Arow = A + (size_t)(aidx ? aidx[m] : m) * strideB;
  int n = nBase + li;
  const float* Wrow = (n < N) ? W + (size_t)n * E : nullptr;
  float4 av = Arow ? *(const float4*)(Arow + lk) : f40();
  float4 wv = Wrow ? *(const float4*)(Wrow + lk) : f40();
  for (int k0 = 0; k0 < E; k0 += 16) {
    As[lk + 0][li] = av.x; As[lk + 1][li] = av.y; As[lk + 2][li] = av.z; As[lk + 3][li] = av.w;
    Ws[lk + 0][li] = wv.x; Ws[lk + 1][li] = wv.y; Ws[lk + 2][li] = wv.z; Ws[lk + 3][li] = wv.w;
    __syncthreads();
    if (k0 + 16 < E) {
      av = Arow ? *(const float4*)(Arow + k0 + 16 + lk) : f40();
      wv = Wrow ? *(const float4*)(Wrow + k0 + 16 + lk) : f40();
    }
    fma16(As, Ws, acc, tx, ty);
    __syncthreads();
  }
#pragma unroll
  for (int r = 0; r < 4; ++r) {
    int mm = mBase + ty * 4 + r;
    if (mm >= M) continue;
#pragma unroll
    for (int c = 0; c < 4; ++c) {
      int nn = nBase + tx * 4 + c;
      if (nn >= N) continue;
      C[(size_t)mm * ldc + nn] = acc[r][c] + (bias ? bias[nn] : 0.f);
    }
  }
}

// ---------- WQKTT[f][j] = sum_c KREL[j][c]*Wq[c][f], stored [f*1024 + j] ----------
__global__ __launch_bounds__(256) void k_ntT(const float* __restrict__ A, int M,
                                             const float* __restrict__ W,
                                             float* __restrict__ CT) {
  __shared__ float As[16][64], Ws[16][64];
  int tid = threadIdx.x, mBase = blockIdx.y * 64, nBase = blockIdx.x * 64;
  int tx = tid & 15, ty = tid >> 4, li = tid & 63, lk = (tid >> 6) * 4;
  int wr = tid >> 6;
  float acc[4][4] = {};
  int m = mBase + li;
  const float* Arow = (m < M) ? A + (size_t)m * E : nullptr;
  for (int k0 = 0; k0 < E; k0 += 16) {
    float4 av = Arow ? *(const float4*)(Arow + k0 + lk) : f40();
    As[lk + 0][li] = av.x; As[lk + 1][li] = av.y; As[lk + 2][li] = av.z; As[lk + 3][li] = av.w;
#pragma unroll
    for (int j = 0; j < 4; ++j)
      Ws[wr * 4 + j][li] = W[(size_t)(k0 + wr * 4 + j) * E + nBase + li];
    __syncthreads();
    fma16(As, Ws, acc, tx, ty);
    __syncthreads();
  }
#pragma unroll
  for (int r = 0; r < 4; ++r) {
    int mm = mBase + ty * 4 + r;   // j index
    if (mm >= M) continue;
#pragma unroll
    for (int c = 0; c < 4; ++c) {
      int nn = nBase + tx * 4 + c;  // f index
      CT[(size_t)nn * 1024 + mm] = acc[r][c];
    }
  }
}

// ---------- GT[f][e] = sum_c Wq[c][f]*Wk[c][e] ----------
__global__ __launch_bounds__(256) void k_tt(const float* __restrict__ A,
                                            const float* __restrict__ Bw,
                                            float* __restrict__ C) {
  __shared__ float As[16][64], Ws[16][64];
  int tid = threadIdx.x, mBase = blockIdx.y * 64, nBase = blockIdx.x * 64;
  int tx = tid & 15, ty = tid >> 4, li = tid & 63;
  int wr = tid >> 6;
  float acc[4][4] = {};
  for (int k0 = 0; k0 < E; k0 += 16) {
#pragma unroll
    for (int j = 0; j < 4; ++j) {
      As[wr * 4 + j][li] = A[(size_t)(k0 + wr * 4 + j) * E + mBase + li];
      Ws[wr * 4 + j][li] = Bw[(size_t)(k0 + wr * 4 + j) * E + nBase + li];
    }
    __syncthreads();
    fma16(As, Ws, acc, tx, ty);
    __syncthreads();
  }
#pragma unroll
  for (int r = 0; r < 4; ++r)
#pragma unroll
    for (int c = 0; c < 4; ++c)
      C[(size_t)(mBase + ty * 4 + r) * E + nBase + tx * 4 + c] = acc[r][c];
}

// ---------- folded bias terms ----------
__global__ __launch_bounds__(256) void k_smalls(const float* __restrict__ KREL,
                                                const float* __restrict__ Wq,
                                                const float* __restrict__ Wk,
                                                const float* __restrict__ bq,
                                                const float* __restrict__ bk,
                                                float* __restrict__ CQS,
                                                float* __restrict__ CYB,
                                                float* __restrict__ CL) {
  __shared__ float sb[256];
  int bid = blockIdx.x, tid = threadIdx.x;
  if (bid < 4) {
    int j = bid * 256 + tid;
    if (j < R) {
      float s = 0.f;
      const float* kr = KREL + (size_t)j * E;
      for (int f = 0; f < E; ++f) s += bq[f] * kr[f];
      CQS[j] = SCALE * s;
    } else {
      CQS[j] = -1e30f;   // pad cols 1000..1023
    }
  } else if (bid < 6) {
    int e = (bid - 4) * 256 + tid;
    float s = 0.f;
    for (int f = 0; f < E; ++f) s += bq[f] * Wk[(size_t)f * E + e] + bk[f] * Wq[(size_t)f * E + e];
    CYB[e] = SCALE * s;
  } else {
    float part = 0.f;
    for (int f = tid; f < E; f += 256) part += bq[f] * bk[f];
    float s = brsum(part, sb);
    if (tid == 0) CL[0] = SCALE * s;
  }
}

// ---------- h1 for worklist entries ----------
__global__ __launch_bounds__(256) void k_h1c(const int* __restrict__ wlb,
                                             const int* __restrict__ wlL,
                                             const float* __restrict__ GI,
                                             const float* __restrict__ bhh,
                                             float* __restrict__ H1C) {
  int w = blockIdx.x;
  const float* gi = GI + (size_t)(wlb[w] * 16 + wlL[w]) * K3;
  float* h = H1C + (size_t)w * E;
  for (int e = threadIdx.x; e < E; e += 256) {
    float r = sigm(gi[e] + bhh[e]);
    float z = sigm(gi[E + e] + bhh[E + e]);
    float n = tanhf(gi[2 * E + e] + r * bhh[2 * E + e]);
    h[e] = (1.f - z) * n;
  }
}

// ---------- fused sel + attention GEMV + softmax + entropy (one WG per batch) ----------
__global__ __launch_bounds__(256) void k_selatt(
    const float* __restrict__ SCR, const float* __restrict__ PAIR,
    int* __restrict__ pos, int P, int* __restrict__ xdst,
    int* __restrict__ wlb, int* __restrict__ wlL, int* __restrict__ wlR,
    float* __restrict__ SP,
    const float* __restrict__ WQKTT, const float* __restrict__ GT,
    const float* __restrict__ CQS, const float* __restrict__ CYB,
    const float* __restrict__ CL,
    float* __restrict__ PROB, float* __restrict__ SC, float* __restrict__ LOSS,
    int t, int writeRaw) {
  __shared__ float sp[E];
  __shared__ float sb[256];
  __shared__ int s_m;
  int b = blockIdx.x, tid = threadIdx.x;
  // ---- sel ----
  if (tid == 0) {
    int L = P + 1;
    int lp[16];
    for (int i = 0; i < L; ++i) lp[i] = pos[b * 16 + i];
    float best = -1e30f; int sel = 0;
    for (int i = 0; i < P; ++i) {
      float v = SCR[b * 16 + lp[i]];
      if (v > best) { best = v; sel = i; }
    }
    int r1i = (sel + 2 < L) ? sel + 2 : L - 1;
    int l1 = lp[sel], r1 = lp[r1i];
    int l0 = (sel > 0) ? lp[sel - 1] : l1;
    int r0 = (sel > 0) ? lp[sel] : r1;
    wlb[2 * b] = b;     wlL[2 * b] = l0;     wlR[2 * b] = r0;
    wlb[2 * b + 1] = b; wlL[2 * b + 1] = l1; wlR[2 * b + 1] = r1;
    xdst[b] = b * 16 + l1;
    for (int i = sel + 1; i < L - 1; ++i) pos[b * 16 + i] = lp[i + 1];
    s_m = l1;
  }
  __syncthreads();
  {
    const float* src = PAIR + (size_t)(b * 16 + s_m) * E;
    for (int e = tid; e < E; e += 256) {
      float v = src[e];
      sp[e] = v;
      SP[(size_t)b * E + e] = v;
    }
  }
  __syncthreads();
  // ---- 1024 scores (4/thread), k-major WQKTT ----
  float d0 = 0.f, d1 = 0.f, d2 = 0.f, d3 = 0.f;
#pragma unroll 4
  for (int k = 0; k < E; ++k) {
    float a = sp[k];
    const float* w = WQKTT + (size_t)k * 1024 + tid;
    d0 = fmaf(a, w[0], d0);
    d1 = fmaf(a, w[256], d1);
    d2 = fmaf(a, w[512], d2);
    d3 = fmaf(a, w[768], d3);
  }
  float s0 = d0 * SCALE + CQS[tid];
  float s1 = d1 * SCALE + CQS[tid + 256];
  float s2 = d2 * SCALE + CQS[tid + 512];
  float s3 = d3 * SCALE + CQS[tid + 768];
  // ---- y (2/thread) and last score ----
  float y0 = 0.f, y1 = 0.f;
#pragma unroll 4
  for (int f = 0; f < E; ++f) {
    float a = sp[f];
    const float* g = GT + (size_t)f * E + tid;
    y0 = fmaf(a, g[0], y0);
    y1 = fmaf(a, g[256], y1);
  }
  y0 = y0 * SCALE + CYB[tid];
  y1 = y1 * SCALE + CYB[tid + 256];
  float part = y0 * sp[tid] + y1 * sp[tid + 256];
  float last = brsum(part, sb) + CL[0];
  // ---- softmax / entropy ----
  float m4 = fmaxf(fmaxf(s0, s1), fmaxf(s2, s3));
  float mx = brmax(fmaxf(m4, last), sb);
  float e0 = expf(s0 - mx), e1 = expf(s1 - mx), e2 = expf(s2 - mx), e3 = expf(s3 - mx);
  float z = brsum(e0 + e1 + e2 + e3, sb);
  float s1s = brsum(e0 * s0 + e1 * s1 + e2 * s2 + e3 * s3, sb);
  float el = expf(last - mx);
  z += el;
  s1s += el * last;
  if (tid == 0) LOSS[b * 16 + t] = mx + logf(z) - s1s / z;
  float inv = 1.f / z;
  if (writeRaw) {
    float* srow = SC + (size_t)b * (R + 1);
    srow[tid] = s0; srow[tid + 256] = s1; srow[tid + 512] = s2;
    if (tid < 232) srow[tid + 768] = s3;
    if (tid == 0) srow[R] = last;
  } else {
    float* prow = PROB + (size_t)b * 1024;
    prow[tid] = e0 * inv; prow[tid + 256] = e1 * inv; prow[tid + 512] = e2 * inv;
    if (tid < 232) prow[tid + 768] = e3 * inv;   // j < 1000
    else if (tid > 232) prow[tid + 768] = 0.f;   // pad j=1001..1023
    if (tid == 0) prow[1000] = el * inv;         // probR
  }
}

// ---------- GI_new[xdst] = PROB @ EW + probR*(SP @ Wih^T) + bih ----------
__global__ __launch_bounds__(256) void k_gg(const float* __restrict__ PROB,
                                            const float* __restrict__ SP,
                                            const float* __restrict__ EW,
                                            const float* __restrict__ Wih,
                                            const float* __restrict__ bih,
                                            const int* __restrict__ xdst,
                                            float* __restrict__ GI) {
  __shared__ float As[16][64], Ws[16][64];
  int tid = threadIdx.x, mBase = blockIdx.y * 64, nBase = blockIdx.x * 64;
  int tx = tid & 15, ty = tid >> 4, li = tid & 63, lk = (tid >> 6) * 4;
  int wr = tid >> 6;
  float acc[4][4] = {};
  int m = mBase + li;  // < 128
  const float* prow = PROB + (size_t)m * 1024;
  // part 1: K=1024 over k-major EW (pad rows zero)
  for (int k0 = 0; k0 < 1024; k0 += 16) {
    float4 av = *(const float4*)(prow + k0 + lk);
    As[lk + 0][li] = av.x; As[lk + 1][li] = av.y; As[lk + 2][li] = av.z; As[lk + 3][li] = av.w;
#pragma unroll
    for (int j = 0; j < 4; ++j)
      Ws[wr * 4 + j][li] = EW[(size_t)(k0 + wr * 4 + j) * K3 + nBase + li];
    __syncthreads();
    fma16(As, Ws, acc, tx, ty);
    __syncthreads();
  }
  // part 2: K=512, A = probR * sp
  float pr = prow[1000];
  const float* sprow = SP + (size_t)m * E;
  const float* Wrow = Wih + (size_t)(nBase + li) * E;
  for (int k0 = 0; k0 < E; k0 += 16) {
    float4 av = *(const float4*)(sprow + k0 + lk);
    As[lk + 0][li] = pr * av.x; As[lk + 1][li] = pr * av.y;
    As[lk + 2][li] = pr * av.z; As[lk + 3][li] = pr * av.w;
    float4 wv = *(const float4*)(Wrow + k0 + lk);
    Ws[lk + 0][li] = wv.x; Ws[lk + 1][li] = wv.y; Ws[lk + 2][li] = wv.z; Ws[lk + 3][li] = wv.w;
    __syncthreads();
    fma16(As, Ws, acc, tx, ty);
    __syncthreads();
  }
#pragma unroll
  for (int r = 0; r < 4; ++r) {
    size_t crow = (size_t)xdst[mBase + ty * 4 + r] * K3;
#pragma unroll
    for (int c = 0; c < 4; ++c) {
      int nn = nBase + tx * 4 + c;
      GI[crow + nn] = acc[r][c] + bih[nn];
    }
  }
}

// ---------- pair body (reads precomputed H1C) ----------
static __device__ void dev_pair(int w, const int* wlb, const int* wlL, const int* wlR,
                                const float* GI, const float* GHC, const float* H1C,
                                const float* wfc, float bfc0,
                                float* PAIR, float* SCR, float* sb) {
  int tid = threadIdx.x;
  int b = wlb[w], ls = wlL[w], rs = wlR[w];
  const float* gir = GI + (size_t)(b * 16 + rs) * K3;
  const float* gh = GHC + (size_t)w * K3;
  const float* h = H1C + (size_t)w * E;
  float* p = PAIR + (size_t)(b * 16 + ls) * E;
  float part = 0.f;
  for (int e = tid; e < E; e += 256) {
    float r = sigm(gir[e] + gh[e]);
    float z = sigm(gir[E + e] + gh[E + e]);
    float n = tanhf(gir[2 * E + e] + r * gh[2 * E + e]);
    float pv = (1.f - z) * n + z * h[e];
    p[e] = pv;
    part += pv * wfc[e];
  }
  float d = brsum(part, sb);
  if (tid == 0) SCR[b * 16 + ls] = sigm(d + bfc0);
}

__global__ __launch_bounds__(256) void k_pairc0(const int* __restrict__ wlb,
                                                const int* __restrict__ wlL,
                                                const int* __restrict__ wlR,
                                                const float* __restrict__ GI,
                                                const float* __restrict__ GHC,
                                                const float* __restrict__ H1C,
                                                const float* __restrict__ wfc,
                                                const float* __restrict__ bfc,
                                                float* __restrict__ PAIR,
                                                float* __restrict__ SCR) {
  __shared__ float sb[256];
  dev_pair(blockIdx.x, wlb, wlL, wlR, GI, GHC, H1C, wfc, bfc[0], PAIR, SCR, sb);
}

__global__ __launch_bounds__(256) void k_pair2(const int* __restrict__ wlb,
                                               const int* __restrict__ wlL,
                                               const int* __restrict__ wlR,
                                               const float* __restrict__ GI,
                                               const float* __restrict__ GHC,
                                               const float* __restrict__ H1C,
                                               const float* __restrict__ wfc,
                                               const float* __restrict__ bfc,
                                               float* __restrict__ PAIR,
                                               float* __restrict__ SCR) {
  __shared__ float sb[256];
  int b = blockIdx.x;
  dev_pair(2 * b, wlb, wlL, wlR, GI, GHC, H1C, wfc, bfc[0], PAIR, SCR, sb);
  dev_pair(2 * b + 1, wlb, wlL, wlR, GI, GHC, H1C, wfc, bfc[0], PAIR, SCR, sb);
}

// ---------- final write ----------
__global__ __launch_bounds__(256) void k_writeout(const float* __restrict__ SC,
                                                  const float* __restrict__ LOSS,
                                                  float* __restrict__ out) {
  int idx = blockIdx.x * 256 + threadIdx.x;
  const int NS = B * (R + 1);
  if (idx < NS) {
    out[idx] = SC[idx];
  } else if (idx < NS + B * 16) {
    int r = idx - NS;
    int t = r & 15;
    out[idx] = (t == 14) ? 0.f : LOSS[r];
  }
}

extern "C" void kernel_launch(void* const* d_in, const int* in_sizes, int n_in,
                              void* d_out, int out_size, void* d_ws, size_t ws_size,
                              hipStream_t stream) {
  (void)in_sizes; (void)n_in; (void)out_size; (void)ws_size;
  const int* tokens = (const int*)d_in[0];
  const float* emb = (const float*)d_in[1];
  const float* W_ih = (const float*)d_in[2];
  const float* W_hh = (const float*)d_in[3];
  const float* b_ih = (const float*)d_in[4];
  const float* b_hh = (const float*)d_in[5];
  const float* w_fc = (const float*)d_in[6];
  const float* b_fc = (const float*)d_in[7];
  const float* Wq = (const float*)d_in[8];
  const float* bq = (const float*)d_in[9];
  const float* Wk = (const float*)d_in[10];
  const float* bk = (const float*)d_in[11];
  float* out = (float*)d_out;

  float* ws = (float*)d_ws;
  size_t o = 0;
  float* GI = ws + o;    o += (size_t)B * 16 * K3;
  float* PAIR = ws + o;  o += (size_t)B * 16 * E;
  float* SCR = ws + o;   o += (size_t)B * 16;
  float* H1C = ws + o;   o += (size_t)NW0 * E;
  float* GHC = ws + o;   o += (size_t)NW0 * K3;
  float* KREL = ws + o;  o += (size_t)R * E;
  float* WQKTT = ws + o; o += (size_t)512 * 1024;
  float* GT = ws + o;    o += (size_t)E * E;
  float* EW = ws + o;    o += (size_t)1024 * K3;
  float* CQS = ws + o;   o += 1024;
  float* CYB = ws + o;   o += 512;
  float* CL = ws + o;    o += 1;
  float* PROB = ws + o;  o += (size_t)B * 1024;
  float* SP = ws + o;    o += (size_t)B * E;
  float* SC = ws + o;    o += (size_t)B * (R + 1);
  float* LOSS = ws + o;  o += (size_t)B * 16;
  int* pos = (int*)(ws + o);  o += B * 16;
  int* wlb = (int*)(ws + o);  o += NW0;
  int* wlL = (int*)(ws + o);  o += NW0;
  int* wlR = (int*)(ws + o);  o += NW0;
  int* xdst = (int*)(ws + o); o += B;

  // ---- init ----
  k_initwl<<<144, 256, 0, stream>>>(pos, wlb, wlL, wlR, EW, WQKTT);
  k_gemm<<<dim3(8, 16), 256, 0, stream>>>(emb, E, R, nullptr, Wk, E, bk, KREL, E);
  k_ntT<<<dim3(8, 16), 256, 0, stream>>>(KREL, R, Wq, WQKTT);
  k_tt<<<dim3(8, 8), 256, 0, stream>>>(Wq, Wk, GT);
  k_smalls<<<7, 256, 0, stream>>>(KREL, Wq, Wk, bq, bk, CQS, CYB, CL);
  k_gemm<<<dim3(24, 16), 256, 0, stream>>>(emb, E, R, nullptr, W_ih, K3, nullptr, EW, K3);
  k_gemm<<<dim3(24, 32), 256, 0, stream>>>(emb, E, B * 16, tokens, W_ih, K3, b_ih, GI, K3);
  k_h1c<<<NW0, 256, 0, stream>>>(wlb, wlL, GI, b_hh, H1C);
  k_gemm<<<dim3(24, 30), 256, 0, stream>>>(H1C, E, NW0, nullptr, W_hh, K3, b_hh, GHC, K3);
  k_pairc0<<<NW0, 256, 0, stream>>>(wlb, wlL, wlR, GI, GHC, H1C, w_fc, b_fc, PAIR, SCR);

  // ---- 14 merge steps ----
  for (int t = 0; t < 14; ++t) {
    k_selatt<<<B, 256, 0, stream>>>(SCR, PAIR, pos, 15 - t, xdst, wlb, wlL, wlR, SP,
                                    WQKTT, GT, CQS, CYB, CL, PROB, SC, LOSS, t, 0);
    k_gg<<<dim3(24, 2), 256, 0, stream>>>(PROB, SP, EW, W_ih, b_ih, xdst, GI);
    k_h1c<<<2 * B, 256, 0, stream>>>(wlb, wlL, GI, b_hh, H1C);
    k_gemm<<<dim3(24, 4), 256, 0, stream>>>(H1C, E, 2 * B, nullptr, W_hh, K3, b_hh, GHC, K3);
    k_pair2<<<B, 256, 0, stream>>>(wlb, wlL, wlR, GI, GHC, H1C, w_fc, b_fc, PAIR, SCR);
  }

  // ---- final attention on the single remaining pair ----
  k_selatt<<<B, 256, 0, stream>>>(SCR, PAIR, pos, 1, xdst, wlb, wlL, wlR, SP,
                                  WQKTT, GT, CQS, CYB, CL, PROB, SC, LOSS, 15, 1);
  k_writeout<<<(B * (R + 1) + B * 16 + 255) / 256, 256, 0, stream>>>(SC, LOSS, out);
}

// Round 10
// 2582.717 us; speedup vs baseline: 1.3991x; 1.3991x over previous
//
#include <hip/hip_runtime.h>

#define B 128
#define S 16
#define E 512
#define R 1000
#define K3 1536
#define NW0 1920
#define NKS 12      // K-slices for the GI gemm (1536/12 = 128)
#define SCALE 0.04419417382415922f

static __device__ __forceinline__ float sigm(float x) { return 1.f / (1.f + expf(-x)); }
static __device__ __forceinline__ float4 f40() { return make_float4(0.f, 0.f, 0.f, 0.f); }

static __device__ __forceinline__ float brsum(float v, float* sb) {
  int tid = threadIdx.x;
  sb[tid] = v; __syncthreads();
  for (int s = 128; s > 0; s >>= 1) {
    if (tid < s) sb[tid] += sb[tid + s];
    __syncthreads();
  }
  float r = sb[0]; __syncthreads();
  return r;
}
static __device__ __forceinline__ float brmax(float v, float* sb) {
  int tid = threadIdx.x;
  sb[tid] = v; __syncthreads();
  for (int s = 128; s > 0; s >>= 1) {
    if (tid < s) sb[tid] = fmaxf(sb[tid], sb[tid + s]);
    __syncthreads();
  }
  float r = sb[0]; __syncthreads();
  return r;
}

static __device__ __forceinline__ void fma16(const float (*__restrict__ As)[64],
                                             const float (*__restrict__ Ws)[64],
                                             float acc[4][4], int tx, int ty) {
#pragma unroll
  for (int k = 0; k < 16; ++k) {
    float4 a4 = *(const float4*)&As[k][ty * 4];
    float4 w4 = *(const float4*)&Ws[k][tx * 4];
    acc[0][0] = fmaf(a4.x, w4.x, acc[0][0]); acc[0][1] = fmaf(a4.x, w4.y, acc[0][1]);
    acc[0][2] = fmaf(a4.x, w4.z, acc[0][2]); acc[0][3] = fmaf(a4.x, w4.w, acc[0][3]);
    acc[1][0] = fmaf(a4.y, w4.x, acc[1][0]); acc[1][1] = fmaf(a4.y, w4.y, acc[1][1]);
    acc[1][2] = fmaf(a4.y, w4.z, acc[1][2]); acc[1][3] = fmaf(a4.y, w4.w, acc[1][3]);
    acc[2][0] = fmaf(a4.z, w4.x, acc[2][0]); acc[2][1] = fmaf(a4.z, w4.y, acc[2][1]);
    acc[2][2] = fmaf(a4.z, w4.z, acc[2][2]); acc[2][3] = fmaf(a4.z, w4.w, acc[2][3]);
    acc[3][0] = fmaf(a4.w, w4.x, acc[3][0]); acc[3][1] = fmaf(a4.w, w4.y, acc[3][1]);
    acc[3][2] = fmaf(a4.w, w4.z, acc[3][2]); acc[3][3] = fmaf(a4.w, w4.w, acc[3][3]);
  }
}

// ---------- init: pos/worklist + zero pads (EWX rows 1000..1023, WQKTT cols) ----------
__global__ __launch_bounds__(256) void k_initwl(int* __restrict__ pos,
                                                int* __restrict__ wlb,
                                                int* __restrict__ wlL,
                                                int* __restrict__ wlR,
                                                float* __restrict__ EWX,
                                                float* __restrict__ WQKTT) {
  int gid = blockIdx.x * 256 + threadIdx.x;
  if (gid < B * 16) pos[gid] = gid & 15;
  if (gid < NW0) {
    wlb[gid] = gid / 15; wlL[gid] = gid % 15; wlR[gid] = gid % 15 + 1;
  }
  if (gid < 24 * K3) EWX[(size_t)1000 * K3 + gid] = 0.f;   // rows 1000..1023
  if (gid < 512 * 24) {
    int r_ = gid / 24, c_ = gid % 24;
    WQKTT[(size_t)r_ * 1024 + 1000 + c_] = 0.f;            // cols 1000..1023
  }
}

// ---------- W_ih transpose into EWX rows 1024..1535: EWX[1024+c][n] = W_ih[n][c] ----------
__global__ __launch_bounds__(256) void k_wt(const float* __restrict__ Wih,
                                            float* __restrict__ EWX) {
  int gid = blockIdx.x * 256 + threadIdx.x;
  if (gid >= 512 * K3) return;
  int c = gid / K3, n = gid - c * K3;
  EWX[(size_t)(1024 + c) * K3 + n] = Wih[(size_t)n * E + c];
}

// ---------- generic GEMM (register-prefetched): C[m,n]=sum_k A[row(m)*sB+k]*W[n*E+k]+bias
__global__ __launch_bounds__(256) void k_gemm(const float* __restrict__ A, int strideB, int M,
                                              const int* __restrict__ aidx,
                                              const float* __restrict__ W, int N,
                                              const float* __restrict__ bias,
                                              float* __restrict__ C, int ldc) {
  __shared__ float As[16][64], Ws[16][64];
  int tid = threadIdx.x, mBase = blockIdx.y * 64, nBase = blockIdx.x * 64;
  int tx = tid & 15, ty = tid >> 4, li = tid & 63, lk = (tid >> 6) * 4;
  float acc[4][4] = {};
  int m = mBase + li;
  const float* Arow = nullptr;
  if (m < M) Arow = A + (size_t)(aidx ? aidx[m] : m) * strideB;
  int n = nBase + li;
  const float* Wrow = (n < N) ? W + (size_t)n * E : nullptr;
  float4 av = Arow ? *(const float4*)(Arow + lk) : f40();
  float4 wv = Wrow ? *(const float4*)(Wrow + lk) : f40();
  for (int k0 = 0; k0 < E; k0 += 16) {
    As[lk + 0][li] = av.x; As[lk + 1][li] = av.y; As[lk + 2][li] = av.z; As[lk + 3][li] = av.w;
    Ws[lk + 0][li] = wv.x; Ws[lk + 1][li] = wv.y; Ws[lk + 2][li] = wv.z; Ws[lk + 3][li] = wv.w;
    __syncthreads();
    if (k0 + 16 < E) {
      av = Arow ? *(const float4*)(Arow + k0 + 16 + lk) : f40();
      wv = Wrow ? *(const float4*)(Wrow + k0 + 16 + lk) : f40();
    }
    fma16(As, Ws, acc, tx, ty);
    __syncthreads();
  }
#pragma unroll
  for (int r = 0; r < 4; ++r) {
    int mm = mBase + ty * 4 + r;
    if (mm >= M) continue;
#pragma unroll
    for (int c = 0; c < 4; ++c) {
      int nn = nBase + tx * 4 + c;
      if (nn >= N) continue;
      C[(size_t)mm * ldc + nn] = acc[r][c] + (bias ? bias[nn] : 0.f);
    }
  }
}

// ---------- WQKTT[f][j] = sum_c KREL[j][c]*Wq[c][f] ----------
__global__ __launch_bounds__(256) void k_ntT(const float* __restrict__ A, int M,
                                             const float* __restrict__ W,
                                             float* __restrict__ CT) {
  __shared__ float As[16][64], Ws[16][64];
  int tid = threadIdx.x, mBase = blockIdx.y * 64, nBase = blockIdx.x * 64;
  int tx = tid & 15, ty = tid >> 4, li = tid & 63, lk = (tid >> 6) * 4;
  int wr = tid >> 6;
  float acc[4][4] = {};
  int m = mBase + li;
  const float* Arow = (m < M) ? A + (size_t)m * E : nullptr;
  for (int k0 = 0; k0 < E; k0 += 16) {
    float4 av = Arow ? *(const float4*)(Arow + k0 + lk) : f40();
    As[lk + 0][li] = av.x; As[lk + 1][li] = av.y; As[lk + 2][li] = av.z; As[lk + 3][li] = av.w;
#pragma unroll
    for (int j = 0; j < 4; ++j)
      Ws[wr * 4 + j][li] = W[(size_t)(k0 + wr * 4 + j) * E + nBase + li];
    __syncthreads();
    fma16(As, Ws, acc, tx, ty);
    __syncthreads();
  }
#pragma unroll
  for (int r = 0; r < 4; ++r) {
    int mm = mBase + ty * 4 + r;
    if (mm >= M) continue;
#pragma unroll
    for (int c = 0; c < 4; ++c)
      CT[(size_t)(nBase + tx * 4 + c) * 1024 + mm] = acc[r][c];
  }
}

// ---------- GT[f][e] = sum_c Wq[c][f]*Wk[c][e] ----------
__global__ __launch_bounds__(256) void k_tt(const float* __restrict__ A,
                                            const float* __restrict__ Bw,
                                            float* __restrict__ C) {
  __shared__ float As[16][64], Ws[16][64];
  int tid = threadIdx.x, mBase = blockIdx.y * 64, nBase = blockIdx.x * 64;
  int tx = tid & 15, ty = tid >> 4, li = tid & 63;
  int wr = tid >> 6;
  float acc[4][4] = {};
  for (int k0 = 0; k0 < E; k0 += 16) {
#pragma unroll
    for (int j = 0; j < 4; ++j) {
      As[wr * 4 + j][li] = A[(size_t)(k0 + wr * 4 + j) * E + mBase + li];
      Ws[wr * 4 + j][li] = Bw[(size_t)(k0 + wr * 4 + j) * E + nBase + li];
    }
    __syncthreads();
    fma16(As, Ws, acc, tx, ty);
    __syncthreads();
  }
#pragma unroll
  for (int r = 0; r < 4; ++r)
#pragma unroll
    for (int c = 0; c < 4; ++c)
      C[(size_t)(mBase + ty * 4 + r) * E + nBase + tx * 4 + c] = acc[r][c];
}

// ---------- folded bias terms ----------
__global__ __launch_bounds__(256) void k_smalls(const float* __restrict__ KREL,
                                                const float* __restrict__ Wq,
                                                const float* __restrict__ Wk,
                                                const float* __restrict__ bq,
                                                const float* __restrict__ bk,
                                                float* __restrict__ CQS,
                                                float* __restrict__ CYB,
                                                float* __restrict__ CL) {
  __shared__ float sb[256];
  int bid = blockIdx.x, tid = threadIdx.x;
  if (bid < 4) {
    int j = bid * 256 + tid;
    if (j < R) {
      float s = 0.f;
      const float* kr = KREL + (size_t)j * E;
      for (int f = 0; f < E; ++f) s += bq[f] * kr[f];
      CQS[j] = SCALE * s;
    } else {
      CQS[j] = -1e30f;
    }
  } else if (bid < 6) {
    int e = (bid - 4) * 256 + tid;
    float s = 0.f;
    for (int f = 0; f < E; ++f) s += bq[f] * Wk[(size_t)f * E + e] + bk[f] * Wq[(size_t)f * E + e];
    CYB[e] = SCALE * s;
  } else {
    float part = 0.f;
    for (int f = tid; f < E; f += 256) part += bq[f] * bk[f];
    float s = brsum(part, sb);
    if (tid == 0) CL[0] = SCALE * s;
  }
}

// ---------- h1 for init worklist ----------
__global__ __launch_bounds__(256) void k_h1c(const int* __restrict__ wlb,
                                             const int* __restrict__ wlL,
                                             const float* __restrict__ GI,
                                             const float* __restrict__ bhh,
                                             float* __restrict__ H1C) {
  int w = blockIdx.x;
  const float* gi = GI + (size_t)(wlb[w] * 16 + wlL[w]) * K3;
  float* h = H1C + (size_t)w * E;
  for (int e = threadIdx.x; e < E; e += 256) {
    float r = sigm(gi[e] + bhh[e]);
    float z = sigm(gi[E + e] + bhh[E + e]);
    float n = tanhf(gi[2 * E + e] + r * bhh[2 * E + e]);
    h[e] = (1.f - z) * n;
  }
}

// ---------- fused sel + attention GEMV + softmax + entropy; writes PROBX ----------
__global__ __launch_bounds__(256) void k_selatt(
    const float* __restrict__ SCR, const float* __restrict__ PAIR,
    int* __restrict__ pos, int P, int* __restrict__ xdst,
    int* __restrict__ wlb, int* __restrict__ wlL, int* __restrict__ wlR,
    const float* __restrict__ WQKTT, const float* __restrict__ GT,
    const float* __restrict__ CQS, const float* __restrict__ CYB,
    const float* __restrict__ CL,
    float* __restrict__ PROBX, float* __restrict__ SC, float* __restrict__ LOSS,
    int t, int writeRaw) {
  __shared__ float sp[E];
  __shared__ float sb[256];
  __shared__ int s_m;
  int b = blockIdx.x, tid = threadIdx.x;
  if (tid == 0) {
    int L = P + 1;
    int lp[16];
    for (int i = 0; i < L; ++i) lp[i] = pos[b * 16 + i];
    float best = -1e30f; int sel = 0;
    for (int i = 0; i < P; ++i) {
      float v = SCR[b * 16 + lp[i]];
      if (v > best) { best = v; sel = i; }
    }
    int r1i = (sel + 2 < L) ? sel + 2 : L - 1;
    int l1 = lp[sel], r1 = lp[r1i];
    int l0 = (sel > 0) ? lp[sel - 1] : l1;
    int r0 = (sel > 0) ? lp[sel] : r1;
    wlb[2 * b] = b;     wlL[2 * b] = l0;     wlR[2 * b] = r0;
    wlb[2 * b + 1] = b; wlL[2 * b + 1] = l1; wlR[2 * b + 1] = r1;
    xdst[b] = b * 16 + l1;
    for (int i = sel + 1; i < L - 1; ++i) pos[b * 16 + i] = lp[i + 1];
    s_m = l1;
  }
  __syncthreads();
  {
    const float* src = PAIR + (size_t)(b * 16 + s_m) * E;
    for (int e = tid; e < E; e += 256) sp[e] = src[e];
  }
  __syncthreads();
  // 1024 scores (4/thread)
  float d0 = 0.f, d1 = 0.f, d2 = 0.f, d3 = 0.f;
#pragma unroll 4
  for (int k = 0; k < E; ++k) {
    float a = sp[k];
    const float* w = WQKTT + (size_t)k * 1024 + tid;
    d0 = fmaf(a, w[0], d0);
    d1 = fmaf(a, w[256], d1);
    d2 = fmaf(a, w[512], d2);
    d3 = fmaf(a, w[768], d3);
  }
  float s0 = d0 * SCALE + CQS[tid];
  float s1 = d1 * SCALE + CQS[tid + 256];
  float s2 = d2 * SCALE + CQS[tid + 512];
  float s3 = d3 * SCALE + CQS[tid + 768];
  // y and last score
  float y0 = 0.f, y1 = 0.f;
#pragma unroll 4
  for (int f = 0; f < E; ++f) {
    float a = sp[f];
    const float* g = GT + (size_t)f * E + tid;
    y0 = fmaf(a, g[0], y0);
    y1 = fmaf(a, g[256], y1);
  }
  y0 = y0 * SCALE + CYB[tid];
  y1 = y1 * SCALE + CYB[tid + 256];
  float part = y0 * sp[tid] + y1 * sp[tid + 256];
  float last = brsum(part, sb) + CL[0];
  // softmax / entropy
  float m4 = fmaxf(fmaxf(s0, s1), fmaxf(s2, s3));
  float mx = brmax(fmaxf(m4, last), sb);
  float e0 = expf(s0 - mx), e1 = expf(s1 - mx), e2 = expf(s2 - mx), e3 = expf(s3 - mx);
  float z = brsum(e0 + e1 + e2 + e3, sb);
  float s1s = brsum(e0 * s0 + e1 * s1 + e2 * s2 + e3 * s3, sb);
  float el = expf(last - mx);
  z += el;
  s1s += el * last;
  if (tid == 0) LOSS[b * 16 + t] = mx + logf(z) - s1s / z;
  float inv = 1.f / z;
  if (writeRaw) {
    float* srow = SC + (size_t)b * (R + 1);
    srow[tid] = s0; srow[tid + 256] = s1; srow[tid + 512] = s2;
    if (tid < 232) srow[tid + 768] = s3;
    if (tid == 0) srow[R] = last;
  } else {
    float pr = el * inv;
    float* prow = PROBX + (size_t)b * K3;
    prow[tid] = e0 * inv; prow[tid + 256] = e1 * inv; prow[tid + 512] = e2 * inv;
    prow[tid + 768] = (tid < 232) ? e3 * inv : 0.f;   // cols 1000..1023 pad 0
    prow[1024 + tid] = pr * sp[tid];
    prow[1280 + tid] = pr * sp[tid + 256];
  }
}

// ---------- GI split-K gemm: GIP[s][m] += PROBX[m,ks]*EWX[ks,:] (576 WGs) ----------
__global__ __launch_bounds__(256) void k_ggp(const float* __restrict__ PROBX,
                                             const float* __restrict__ EWX,
                                             float* __restrict__ GIP) {
  __shared__ float As[16][64], Ws[16][64];
  int tid = threadIdx.x;
  int nBase = blockIdx.x * 64, mBase = blockIdx.y * 64;
  int kbeg = blockIdx.z * 128;
  int tx = tid & 15, ty = tid >> 4, li = tid & 63, lk = (tid >> 6) * 4;
  int wr = tid >> 6;
  float acc[4][4] = {};
  int m = mBase + li;   // < 128
  const float* Arow = PROBX + (size_t)m * K3 + kbeg;
  float4 av = *(const float4*)(Arow + lk);
  float w4r[4];
#pragma unroll
  for (int j = 0; j < 4; ++j)
    w4r[j] = EWX[(size_t)(kbeg + wr * 4 + j) * K3 + nBase + li];
  for (int k0 = 0; k0 < 128; k0 += 16) {
    As[lk + 0][li] = av.x; As[lk + 1][li] = av.y; As[lk + 2][li] = av.z; As[lk + 3][li] = av.w;
#pragma unroll
    for (int j = 0; j < 4; ++j) Ws[wr * 4 + j][li] = w4r[j];
    __syncthreads();
    if (k0 + 16 < 128) {
      av = *(const float4*)(Arow + k0 + 16 + lk);
#pragma unroll
      for (int j = 0; j < 4; ++j)
        w4r[j] = EWX[(size_t)(kbeg + k0 + 16 + wr * 4 + j) * K3 + nBase + li];
    }
    fma16(As, Ws, acc, tx, ty);
    __syncthreads();
  }
  float* pt = GIP + (size_t)blockIdx.z * B * K3;
#pragma unroll
  for (int r = 0; r < 4; ++r) {
    int mm = mBase + ty * 4 + r;
#pragma unroll
    for (int c = 0; c < 4; ++c)
      pt[(size_t)mm * K3 + nBase + tx * 4 + c] = acc[r][c];
  }
}

// ---------- reduce 12 partials + bias -> GI[xdst]; compute both step h1 rows ----------
__global__ __launch_bounds__(256) void k_redh1(const float* __restrict__ GIP,
                                               const float* __restrict__ bih,
                                               const int* __restrict__ xdst,
                                               const int* __restrict__ wlL,
                                               const float* __restrict__ bhh,
                                               float* __restrict__ GI,
                                               float* __restrict__ H1C) {
  __shared__ float gnew[K3];
  int b = blockIdx.x, tid = threadIdx.x;
  int xr = xdst[b];
  for (int n = tid; n < K3; n += 256) {
    float v = bih[n];
#pragma unroll
    for (int s = 0; s < NKS; ++s) v += GIP[((size_t)s * B + b) * K3 + n];
    gnew[n] = v;
    GI[(size_t)xr * K3 + n] = v;
  }
  __syncthreads();
  int ls0 = wlL[2 * b];
  const float* g0 = (b * 16 + ls0 == xr) ? (const float*)gnew
                                         : (GI + (size_t)(b * 16 + ls0) * K3);
  for (int e = tid; e < E; e += 256) {
    float r0 = sigm(g0[e] + bhh[e]);
    float z0 = sigm(g0[E + e] + bhh[E + e]);
    float n0 = tanhf(g0[2 * E + e] + r0 * bhh[2 * E + e]);
    H1C[(size_t)(2 * b) * E + e] = (1.f - z0) * n0;
    float r1 = sigm(gnew[e] + bhh[e]);
    float z1 = sigm(gnew[E + e] + bhh[E + e]);
    float n1 = tanhf(gnew[2 * E + e] + r1 * bhh[2 * E + e]);
    H1C[(size_t)(2 * b + 1) * E + e] = (1.f - z1) * n1;
  }
}

// ---------- pair body (reads precomputed H1C) ----------
static __device__ void dev_pair(int w, const int* wlb, const int* wlL, const int* wlR,
                                const float* GI, const float* GHC, const float* H1C,
                                const float* wfc, float bfc0,
                                float* PAIR, float* SCR, float* sb) {
  int tid = threadIdx.x;
  int b = wlb[w], ls = wlL[w], rs = wlR[w];
  const float* gir = GI + (size_t)(b * 16 + rs) * K3;
  const float* gh = GHC + (size_t)w * K3;
  const float* h = H1C + (size_t)w * E;
  float* p = PAIR + (size_t)(b * 16 + ls) * E;
  float part = 0.f;
  for (int e = tid; e < E; e += 256) {
    float r = sigm(gir[e] + gh[e]);
    float z = sigm(gir[E + e] + gh[E + e]);
    float n = tanhf(gir[2 * E + e] + r * gh[2 * E + e]);
    float pv = (1.f - z) * n + z * h[e];
    p[e] = pv;
    part += pv * wfc[e];
  }
  float d = brsum(part, sb);
  if (tid == 0) SCR[b * 16 + ls] = sigm(d + bfc0);
}

__global__ __launch_bounds__(256) void k_pairc0(const int* __restrict__ wlb,
                                                const int* __restrict__ wlL,
                                                const int* __restrict__ wlR,
                                                const float* __restrict__ GI,
                                                const float* __restrict__ GHC,
                                                const float* __restrict__ H1C,
                                                const float* __restrict__ wfc,
                                                const float* __restrict__ bfc,
                                                float* __restrict__ PAIR,
                                                float* __restrict__ SCR) {
  __shared__ float sb[256];
  dev_pair(blockIdx.x, wlb, wlL, wlR, GI, GHC, H1C, wfc, bfc[0], PAIR, SCR, sb);
}

__global__ __launch_bounds__(256) void k_pair2(const int* __restrict__ wlb,
                                               const int* __restrict__ wlL,
                                               const int* __restrict__ wlR,
                                               const float* __restrict__ GI,
                                               const float* __restrict__ GHC,
                                               const float* __restrict__ H1C,
                                               const float* __restrict__ wfc,
                                               const float* __restrict__ bfc,
                                               float* __restrict__ PAIR,
                                               float* __restrict__ SCR) {
  __shared__ float sb[256];
  int b = blockIdx.x;
  dev_pair(2 * b, wlb, wlL, wlR, GI, GHC, H1C, wfc, bfc[0], PAIR, SCR, sb);
  dev_pair(2 * b + 1, wlb, wlL, wlR, GI, GHC, H1C, wfc, bfc[0], PAIR, SCR, sb);
}

// ---------- final write ----------
__global__ __launch_bounds__(256) void k_writeout(const float* __restrict__ SC,
                                                  const float* __restrict__ LOSS,
                                                  float* __restrict__ out) {
  int idx = blockIdx.x * 256 + threadIdx.x;
  const int NS = B * (R + 1);
  if (idx < NS) {
    out[idx] = SC[idx];
  } else if (idx < NS + B * 16) {
    int r = idx - NS;
    int t = r & 15;
    out[idx] = (t == 14) ? 0.f : LOSS[r];
  }
}

extern "C" void kernel_launch(void* const* d_in, const int* in_sizes, int n_in,
                              void* d_out, int out_size, void* d_ws, size_t ws_size,
                              hipStream_t stream) {
  (void)in_sizes; (void)n_in; (void)out_size; (void)ws_size;
  const int* tokens = (const int*)d_in[0];
  const float* emb = (const float*)d_in[1];
  const float* W_ih = (const float*)d_in[2];
  const float* W_hh = (const float*)d_in[3];
  const float* b_ih = (const float*)d_in[4];
  const float* b_hh = (const float*)d_in[5];
  const float* w_fc = (const float*)d_in[6];
  const float* b_fc = (const float*)d_in[7];
  const float* Wq = (const float*)d_in[8];
  const float* bq = (const float*)d_in[9];
  const float* Wk = (const float*)d_in[10];
  const float* bk = (const float*)d_in[11];
  float* out = (float*)d_out;

  float* ws = (float*)d_ws;
  size_t o = 0;
  float* GI = ws + o;    o += (size_t)B * 16 * K3;
  float* PAIR = ws + o;  o += (size_t)B * 16 * E;
  float* SCR = ws + o;   o += (size_t)B * 16;
  float* H1C = ws + o;   o += (size_t)NW0 * E;
  float* GHC = ws + o;   o += (size_t)NW0 * K3;
  float* GIP = GHC + (size_t)256 * K3;            // overlay on GHC rows 256.. (init-only)
  float* KREL = ws + o;  o += (size_t)R * E;
  float* WQKTT = ws + o; o += (size_t)512 * 1024;
  float* GT = ws + o;    o += (size_t)E * E;
  float* EWX = ws + o;   o += (size_t)K3 * K3;
  float* CQS = ws + o;   o += 1024;
  float* CYB = ws + o;   o += 512;
  float* CL = ws + o;    o += 1;
  float* PROBX = ws + o; o += (size_t)B * K3;
  float* SC = ws + o;    o += (size_t)B * (R + 1);
  float* LOSS = ws + o;  o += (size_t)B * 16;
  int* pos = (int*)(ws + o);  o += B * 16;
  int* wlb = (int*)(ws + o);  o += NW0;
  int* wlL = (int*)(ws + o);  o += NW0;
  int* wlR = (int*)(ws + o);  o += NW0;
  int* xdst = (int*)(ws + o); o += B;

  // ---- init ----
  k_initwl<<<144, 256, 0, stream>>>(pos, wlb, wlL, wlR, EWX, WQKTT);
  k_wt<<<(512 * K3 + 255) / 256, 256, 0, stream>>>(W_ih, EWX);
  k_gemm<<<dim3(8, 16), 256, 0, stream>>>(emb, E, R, nullptr, Wk, E, bk, KREL, E);
  k_ntT<<<dim3(8, 16), 256, 0, stream>>>(KREL, R, Wq, WQKTT);
  k_tt<<<dim3(8, 8), 256, 0, stream>>>(Wq, Wk, GT);
  k_smalls<<<7, 256, 0, stream>>>(KREL, Wq, Wk, bq, bk, CQS, CYB, CL);
  k_gemm<<<dim3(24, 16), 256, 0, stream>>>(emb, E, R, nullptr, W_ih, K3, nullptr, EWX, K3);
  k_gemm<<<dim3(24, 32), 256, 0, stream>>>(emb, E, B * 16, tokens, W_ih, K3, b_ih, GI, K3);
  k_h1c<<<NW0, 256, 0, stream>>>(wlb, wlL, GI, b_hh, H1C);
  k_gemm<<<dim3(24, 30), 256, 0, stream>>>(H1C, E, NW0, nullptr, W_hh, K3, b_hh, GHC, K3);
  k_pairc0<<<NW0, 256, 0, stream>>>(wlb, wlL, wlR, GI, GHC, H1C, w_fc, b_fc, PAIR, SCR);

  // ---- 14 merge steps ----
  for (int t = 0; t < 14; ++t) {
    k_selatt<<<B, 256, 0, stream>>>(SCR, PAIR, pos, 15 - t, xdst, wlb, wlL, wlR,
                                    WQKTT, GT, CQS, CYB, CL, PROBX, SC, LOSS, t, 0);
    k_ggp<<<dim3(24, 2, NKS), 256, 0, stream>>>(PROBX, EWX, GIP);
    k_redh1<<<B, 256, 0, stream>>>(GIP, b_ih, xdst, wlL, b_hh, GI, H1C);
    k_gemm<<<dim3(24, 4), 256, 0, stream>>>(H1C, E, 2 * B, nullptr, W_hh, K3, b_hh, GHC, K3);
    k_pair2<<<B, 256, 0, stream>>>(wlb, wlL, wlR, GI, GHC, H1C, w_fc, b_fc, PAIR, SCR);
  }

  // ---- final attention on the single remaining pair ----
  k_selatt<<<B, 256, 0, stream>>>(SCR, PAIR, pos, 1, xdst, wlb, wlL, wlR,
                                  WQKTT, GT, CQS, CYB, CL, PROBX, SC, LOSS, 15, 1);
  k_writeout<<<(B * (R + 1) + B * 16 + 255) / 256, 256, 0, stream>>>(SC, LOSS, out);
}